// Round 4
// baseline (341.002 us; speedup 1.0000x reference)
//
#include <hip/hip_runtime.h>

// GCN forward, reassociated + bf16 tables + MFMA GEMMs + single-pass ELL:
//   y1b = bf16(x @ W1)                  (MFMA GEMM, fused into ELL build)
//   h2  = relu(A @ y1b + b1)            (LDS-resident, never hits global)
//   y2b = bf16(h2 @ W2)                 (MFMA, fused with the SpMM above)
//   out = A @ y2b + b2                  (SpMM 64-wide gather, fp32 out)
// Round 15: dual-bucket cursors. Fill is insensitive to payload width, NT,
// and line padding (R12-R14) -> theory: same-address atomic serialization
// (deg~16 RMW chain per row cursor). Split each row into 2x32-slot buckets
// (bucket = col&1, random) with cursors in separate arrays -> chain length
// halves (Poisson(8)/bucket, overflow P(>32)~1e-10). SpMM reads each bucket
// with its own short branchless loop.

typedef __attribute__((ext_vector_type(8))) short short8;
typedef __attribute__((ext_vector_type(4))) float floatx4;
typedef __attribute__((ext_vector_type(2))) float floatx2;

#define ELLS 64    // slots/row total: 2 buckets x 32
#define BCAP 32    // per-bucket capacity
#define H2LD 136   // LDS row stride in shorts (128 + 8 pad)
#define CURS 16    // cursor padding: one int per 64B line

static __device__ __forceinline__ unsigned short f2bf(float f) {
    unsigned int u = __builtin_bit_cast(unsigned int, f);
    u += 0x7fffu + ((u >> 16) & 1u);        // round-to-nearest-even
    return (unsigned short)(u >> 16);
}
static __device__ __forceinline__ float bflo(unsigned int u) {
    return __builtin_bit_cast(float, u << 16);
}
static __device__ __forceinline__ float bfhi(unsigned int u) {
    return __builtin_bit_cast(float, u & 0xffff0000u);
}
// packed ELL slot helpers: low 17 bits = col, high 15 bits = val*32767
static __device__ __forceinline__ float slotval(unsigned int s) {
    return (float)(s >> 17) * (1.0f / 32767.0f);
}

// ---------------------------------------------------------------------------
// Prep: zero cursors[2*N*CURS] (coalesced); W1[128,128] -> W1t[128][128] bf16;
//       W2[128,64] -> W2t[64][128] bf16
// ---------------------------------------------------------------------------
__global__ __launch_bounds__(256) void prep_kernel(
    const float* __restrict__ W1, const float* __restrict__ W2,
    unsigned short* __restrict__ W1t, unsigned short* __restrict__ W2t,
    int* __restrict__ cursor, int N)
{
    int idx = blockIdx.x * 256 + threadIdx.x;
    int stride = gridDim.x * 256;
    for (int i = idx; i < 2 * N * CURS; i += stride) cursor[i] = 0;
    if (idx < 128 * 128) {
        int n = idx >> 7, k = idx & 127;
        W1t[idx] = f2bf(W1[(size_t)k * 128 + n]);
    }
    if (idx < 64 * 128) {
        int n = idx >> 7, k = idx & 127;
        W2t[idx] = f2bf(W2[(size_t)k * 64 + n]);
    }
}

// ---------------------------------------------------------------------------
// MFMA GEMM body (gemm1): Y[N,128] = bf16(A[N,128] @ W1).
// Verified gfx950 layouts: A/B frag [lane&15][quad*8+j]; C/D col=lane&15,
// row=quad*4+reg. x read exactly once -> NT.
// ---------------------------------------------------------------------------
static __device__ __forceinline__ void gemm1_body(
    const float* __restrict__ A, const unsigned short* __restrict__ Wt,
    unsigned short* __restrict__ Y, int N, int bid)
{
    const int lane = threadIdx.x & 63;
    const int wave = threadIdx.x >> 6;
    const int quad = lane >> 4;
    const int l16  = lane & 15;
    const int row0 = bid * 64 + wave * 16;
    int arow = row0 + l16;
    if (arow > N - 1) arow = N - 1;      // clamp: stores guarded below

    short8 af[4];
    const float* ap = A + (size_t)arow * 128 + quad * 8;
    #pragma unroll
    for (int kt = 0; kt < 4; ++kt) {
        const floatx4* p = (const floatx4*)(ap + kt * 32);
        floatx4 lo = __builtin_nontemporal_load(p);
        floatx4 hi = __builtin_nontemporal_load(p + 1);
        short8 t;
        t[0] = (short)f2bf(lo[0]); t[1] = (short)f2bf(lo[1]);
        t[2] = (short)f2bf(lo[2]); t[3] = (short)f2bf(lo[3]);
        t[4] = (short)f2bf(hi[0]); t[5] = (short)f2bf(hi[1]);
        t[6] = (short)f2bf(hi[2]); t[7] = (short)f2bf(hi[3]);
        af[kt] = t;
    }

    floatx4 acc[8];
    #pragma unroll
    for (int nt = 0; nt < 8; ++nt) acc[nt] = (floatx4){0.f, 0.f, 0.f, 0.f};

    #pragma unroll
    for (int nt = 0; nt < 8; ++nt) {
        const unsigned short* wp = Wt + (size_t)(nt * 16 + l16) * 128 + quad * 8;
        #pragma unroll
        for (int kt = 0; kt < 4; ++kt) {
            short8 bfr = *(const short8*)(wp + kt * 32);
            acc[nt] = __builtin_amdgcn_mfma_f32_16x16x32_bf16(
                af[kt], bfr, acc[nt], 0, 0, 0);
        }
    }

    #pragma unroll
    for (int nt = 0; nt < 8; ++nt) {
        int col = nt * 16 + l16;
        #pragma unroll
        for (int r = 0; r < 4; ++r) {
            int row = row0 + quad * 4 + r;
            if (row < N)
                Y[(size_t)row * 128 + col] = f2bf(acc[nt][r]);
        }
    }
}

// ---------------------------------------------------------------------------
// Fused dispatch:
//  blocks [0, FB): XCD-range-filtered single-pass ELL build, dual-bucket
//    cursors (bucket = col&1 -> slots [0,32) or [32,64)).
//  blocks [FB,..): gemm1 (x@W1 MFMA).
// ---------------------------------------------------------------------------
__global__ __launch_bounds__(256) void fill_ell_gemm1_fused(
    const int* __restrict__ erow, const int* __restrict__ ecol,
    const float* __restrict__ eval, int* __restrict__ cursor,
    unsigned int* __restrict__ ell, int E, int FB, int RSTEP,
    const float* __restrict__ x, const unsigned short* __restrict__ W1t,
    unsigned short* __restrict__ y1b, int N)
{
    if ((int)blockIdx.x < FB) {
        const int g     = blockIdx.x & 7;
        const int chunk = blockIdx.x >> 3;
        const int lo = g * RSTEP;
        const int span = min(RSTEP, N - lo);
        int base = chunk * 1024 + (int)threadIdx.x * 4;
        if (base >= E) return;

        if (base + 4 <= E) {
            int4   r4 = *(const int4*)(erow + base);
            int4   c4 = *(const int4*)(ecol + base);
            float4 v4 = *(const float4*)(eval + base);
            int   rr[4] = {r4.x, r4.y, r4.z, r4.w};
            int   cc[4] = {c4.x, c4.y, c4.z, c4.w};
            float vv[4] = {v4.x, v4.y, v4.z, v4.w};
            #pragma unroll
            for (int j = 0; j < 4; ++j) {
                int r = rr[j];
                if ((unsigned)(r - lo) < (unsigned)span) {
                    int k = cc[j] & 1;
                    int p = atomicAdd(
                        &cursor[((size_t)r + (k ? (size_t)N : 0)) * CURS], 1);
                    if (p < BCAP) {  // never taken; avoids OOB
                        unsigned int pk = (unsigned int)cc[j]
                            | ((unsigned int)(int)(vv[j] * 32767.f + 0.5f) << 17);
                        ell[((size_t)r << 6) + (k << 5) + p] = pk;
                    }
                }
            }
        } else {
            for (int j = 0; j < 4; ++j) {
                int e = base + j;
                if (e < E) {
                    int r = erow[e];
                    if ((unsigned)(r - lo) < (unsigned)span) {
                        int c = ecol[e];
                        int k = c & 1;
                        int p = atomicAdd(
                            &cursor[((size_t)r + (k ? (size_t)N : 0)) * CURS], 1);
                        if (p < BCAP) {
                            unsigned int pk = (unsigned int)c
                                | ((unsigned int)(int)(eval[e] * 32767.f + 0.5f) << 17);
                            ell[((size_t)r << 6) + (k << 5) + p] = pk;
                        }
                    }
                }
            }
        }
    } else {
        gemm1_body(x, W1t, y1b, N, blockIdx.x - FB);
    }
}

// ---------------------------------------------------------------------------
// FUSED layer-1 SpMM + gemm2: block = 1024 threads = 16 waves.
//  Phase 1: wave w gathers row (blockIdx*16 + w); two branchless 8-deep
//    loops, one per bucket (invalid slots predicated to slot=0 -> col 0,
//    val 0), bias+relu, stores the 128-feat bf16 row to LDS.
//  Phase 2 (after barrier): waves 0..3 each compute one 16x16 col-tile of
//    y2 = h2 @ W2 via 4 MFMAs, A-frags straight from LDS, store y2b bf16.
// ---------------------------------------------------------------------------
__global__ __launch_bounds__(1024, 8) void spmm128_gemm2_fused(
    const int* __restrict__ deg, const unsigned int* __restrict__ ell,
    const unsigned short* __restrict__ y1b, const float* __restrict__ b1,
    const unsigned short* __restrict__ W2t,
    unsigned short* __restrict__ y2b, int N)
{
    __shared__ unsigned short h2s[16 * H2LD];

    const int wave = threadIdx.x >> 6;   // 0..15 = row within tile
    const int lane = threadIdx.x & 63;   // owns feats {2*lane, 2*lane+1}
    const int row  = blockIdx.x * 16 + wave;

    unsigned int pack = 0;
    if (row < N) {
        const unsigned int* xf = (const unsigned int*)y1b;
        int dA = min(deg[(size_t)row * CURS], BCAP);
        int dB = min(deg[((size_t)N + row) * CURS], BCAP);
        const unsigned int* ep = ell + ((size_t)row << 6);

        float ax[8], ay[8];
        #pragma unroll
        for (int j = 0; j < 8; ++j) { ax[j] = 0.f; ay[j] = 0.f; }

        #pragma unroll
        for (int h = 0; h < 2; ++h) {
            int d = h ? dB : dA;
            const unsigned int* e2 = ep + (h << 5);
            int d8 = (d + 7) & ~7;
            for (int i = 0; i < d8; i += 8) {
                uint4 q0 = *(const uint4*)(e2 + i);
                uint4 q1 = *(const uint4*)(e2 + i + 4);
                unsigned int s[8] = {q0.x, q0.y, q0.z, q0.w,
                                     q1.x, q1.y, q1.z, q1.w};
                unsigned int sv[8];
                unsigned int u[8];
                #pragma unroll
                for (int j = 0; j < 8; ++j) {
                    unsigned int ss = (i + j < d) ? s[j] : 0u;  // predicated
                    sv[j] = ss;
                    u[j] = xf[((ss & 0x1FFFFu) << 6) | (unsigned)lane];
                }
                #pragma unroll
                for (int j = 0; j < 8; ++j) {
                    float vvv = slotval(sv[j]);
                    ax[j] = fmaf(vvv, bflo(u[j]), ax[j]);
                    ay[j] = fmaf(vvv, bfhi(u[j]), ay[j]);
                }
            }
        }
        float2 b = ((const float2*)b1)[lane];
        float sx = ((ax[0] + ax[1]) + (ax[2] + ax[3]))
                 + ((ax[4] + ax[5]) + (ax[6] + ax[7])) + b.x;
        float sy = ((ay[0] + ay[1]) + (ay[2] + ay[3]))
                 + ((ay[4] + ay[5]) + (ay[6] + ay[7])) + b.y;
        sx = fmaxf(sx, 0.f);
        sy = fmaxf(sy, 0.f);
        pack = (unsigned int)f2bf(sx) | ((unsigned int)f2bf(sy) << 16);
    }
    ((unsigned int*)(h2s + wave * H2LD))[lane] = pack;
    __syncthreads();

    // Phase 2: waves 0..3 -> col-tile nt = wave
    if (wave < 4) {
        const int quad = lane >> 4;
        const int l16  = lane & 15;
        const int nt   = wave;

        short8 af[4];
        #pragma unroll
        for (int kt = 0; kt < 4; ++kt)
            af[kt] = *(const short8*)(h2s + l16 * H2LD + quad * 8 + kt * 32);

        floatx4 acc = (floatx4){0.f, 0.f, 0.f, 0.f};
        const unsigned short* wp = W2t + (size_t)(nt * 16 + l16) * 128 + quad * 8;
        #pragma unroll
        for (int kt = 0; kt < 4; ++kt) {
            short8 bfr = *(const short8*)(wp + kt * 32);
            acc = __builtin_amdgcn_mfma_f32_16x16x32_bf16(af[kt], bfr, acc, 0, 0, 0);
        }

        int col = nt * 16 + l16;
        #pragma unroll
        for (int r = 0; r < 4; ++r) {
            int grow = blockIdx.x * 16 + quad * 4 + r;
            if (grow < N)
                y2b[(size_t)grow * 64 + col] = f2bf(acc[r]);
        }
    }
}

// ---------------------------------------------------------------------------
// SpMM 64-wide (ELL, packed 4B slots, dual bucket): wave per row; half h
// owns bucket h (slots [h*32, h*32+d_h)), 4-deep branchless loop per half,
// 8 gathers/wave in flight. shfl_xor(32) combine.
// ---------------------------------------------------------------------------
__global__ __launch_bounds__(256) void spmm_gather64_out(
    const int* __restrict__ deg, const unsigned int* __restrict__ ell,
    const unsigned short* __restrict__ y2b,
    const float* __restrict__ bias, float* __restrict__ out, int N)
{
    int row = (blockIdx.x * 256 + threadIdx.x) >> 6;
    if (row >= N) return;
    int lane = threadIdx.x & 63;
    int half = lane >> 5, fl = lane & 31;
    const unsigned int* xf = (const unsigned int*)y2b;

    int d = min(deg[((size_t)row + (half ? (size_t)N : 0)) * CURS], BCAP);
    int d4 = (d + 3) & ~3;
    const unsigned int* ep = ell + ((size_t)row << 6) + (half << 5);

    float ax[4], ay[4];
    #pragma unroll
    for (int j = 0; j < 4; ++j) { ax[j] = 0.f; ay[j] = 0.f; }

    for (int i = 0; i < d4; i += 4) {
        uint4 q = *(const uint4*)(ep + i);
        unsigned int s[4] = {q.x, q.y, q.z, q.w};
        unsigned int sv[4];
        unsigned int u[4];
        #pragma unroll
        for (int j = 0; j < 4; ++j) {
            unsigned int ss = (i + j < d) ? s[j] : 0u;
            sv[j] = ss;
            u[j] = xf[((ss & 0x1FFFFu) << 5) | (unsigned)fl];
        }
        #pragma unroll
        for (int j = 0; j < 4; ++j) {
            float vvv = slotval(sv[j]);
            ax[j] = fmaf(vvv, bflo(u[j]), ax[j]);
            ay[j] = fmaf(vvv, bfhi(u[j]), ay[j]);
        }
    }
    float sx = (ax[0] + ax[1]) + (ax[2] + ax[3]);
    float sy = (ay[0] + ay[1]) + (ay[2] + ay[3]);
    sx += __shfl_xor(sx, 32);
    sy += __shfl_xor(sy, 32);
    if (half == 0) {
        float2 b = ((const float2*)bias)[fl];
        floatx2 o; o[0] = sx + b.x; o[1] = sy + b.y;
        __builtin_nontemporal_store(o, (floatx2*)out + (size_t)row * 32 + fl);
    }
}

extern "C" void kernel_launch(void* const* d_in, const int* in_sizes, int n_in,
                              void* d_out, int out_size, void* d_ws, size_t ws_size,
                              hipStream_t stream)
{
    const float* x    = (const float*)d_in[0];
    const int*   erow = (const int*)  d_in[1];
    const int*   ecol = (const int*)  d_in[2];
    const float* eval = (const float*)d_in[3];
    const float* W1   = (const float*)d_in[4];
    const float* b1   = (const float*)d_in[5];
    const float* W2   = (const float*)d_in[6];
    const float* b2   = (const float*)d_in[7];
    float*       out  = (float*)d_out;

    const int N = in_sizes[0] / 128;   // 100000
    const int E = in_sizes[1];         // 1600000
    const int NP = N + 64;             // pad so clamped loads stay in-buffer

    // Workspace (~78 MB)
    unsigned short* y1b = (unsigned short*)d_ws;          // [NP,128] bf16
    unsigned short* y2b = y1b + (size_t)NP * 128;         // [NP,64]  bf16
    unsigned short* W1t = y2b + (size_t)NP * 64;          // [128,128] bf16
    unsigned short* W2t = W1t + 128 * 128;                // [64,128]  bf16
    unsigned int* ell   = (unsigned int*)(W2t + 64 * 128);// [N*64] packed slot
    int*   cursor = (int*)(ell + (size_t)N * ELLS);       // [2*N*CURS] padded

    const int spmm_blocks  = (N + 3) / 4;
    const int fused_blocks = (N + 15) / 16;               // 6250
    const int mfma_blocks  = (N + 63) / 64;               // 1563
    const int prep_blocks  = (N + 255) / 256;
    const int RSTEP        = (N + 7) / 8;                 // rows per XCD range
    const int chunks       = (E + 1023) / 1024;           // 1563
    const int FB           = 8 * chunks;                  // fill blocks

    // ---- Prep: zero cursors, cast/transpose weights ----
    prep_kernel<<<prep_blocks, 256, 0, stream>>>(W1, W2, W1t, W2t, cursor, N);

    // ---- Fused: XCD-filtered single-pass ELL build + gemm1 = bf16(x@W1) ----
    fill_ell_gemm1_fused<<<FB + mfma_blocks, 256, 0, stream>>>(
        erow, ecol, eval, cursor, ell, E, FB, RSTEP, x, W1t, y1b, N);

    // ---- Fused layer-1 SpMM + gemm2: y2b = bf16(relu(A@y1b + b1) @ W2) ----
    spmm128_gemm2_fused<<<fused_blocks, 1024, 0, stream>>>(
        cursor, ell, y1b, b1, W2t, y2b, N);

    // ---- Layer 2 SpMM: out = A@y2b + b2 ----
    spmm_gather64_out<<<spmm_blocks, 256, 0, stream>>>(
        cursor, ell, y2b, b2, out, N);
}

// Round 5
// 328.173 us; speedup vs baseline: 1.0391x; 1.0391x over previous
//
#include <hip/hip_runtime.h>

// GCN forward, reassociated + bf16 tables + MFMA GEMMs + single-pass ELL:
//   y1b = bf16(x @ W1)                  (MFMA GEMM, fused into ELL build)
//   h2  = relu(A @ y1b + b1)            (LDS-resident, never hits global)
//   y2b = bf16(h2 @ W2)                 (MFMA, fused with the SpMM above)
//   out = A @ y2b + b2                  (SpMM 64-wide gather, fp32 out)
// Round 16: base = R3 (single line-padded cursor, packed 4B slots, 328 us).
// Fill scan restructured for atomic MLP: 8 edges/thread, two-phase split —
// phase 1 issues all 8 predicated atomicAdds back-to-back (no dependent op
// inside the branch body), phase 2 does the 8 predicated ELL stores after
// one waitcnt. Exposes 8 overlapping ~700cy memory-side atomic round-trips
// per thread instead of serial chains (theory: that serialization, not
// traffic/contention, is fill's 126 us).

typedef __attribute__((ext_vector_type(8))) short short8;
typedef __attribute__((ext_vector_type(4))) float floatx4;
typedef __attribute__((ext_vector_type(2))) float floatx2;

#define ELLS 64    // ELL stride (slots/row); Poisson(16), 12 sigma headroom
#define H2LD 136   // LDS row stride in shorts (128 + 8 pad)
#define CURS 16    // cursor padding: one int per 64B line

static __device__ __forceinline__ unsigned short f2bf(float f) {
    unsigned int u = __builtin_bit_cast(unsigned int, f);
    u += 0x7fffu + ((u >> 16) & 1u);        // round-to-nearest-even
    return (unsigned short)(u >> 16);
}
static __device__ __forceinline__ float bflo(unsigned int u) {
    return __builtin_bit_cast(float, u << 16);
}
static __device__ __forceinline__ float bfhi(unsigned int u) {
    return __builtin_bit_cast(float, u & 0xffff0000u);
}
// packed ELL slot helpers: low 17 bits = col, high 15 bits = val*32767
static __device__ __forceinline__ float slotval(unsigned int s) {
    return (float)(s >> 17) * (1.0f / 32767.0f);
}

// ---------------------------------------------------------------------------
// Prep: zero cursor[N*CURS] (coalesced); W1[128,128] -> W1t[128][128] bf16;
//       W2[128,64] -> W2t[64][128] bf16
// ---------------------------------------------------------------------------
__global__ __launch_bounds__(256) void prep_kernel(
    const float* __restrict__ W1, const float* __restrict__ W2,
    unsigned short* __restrict__ W1t, unsigned short* __restrict__ W2t,
    int* __restrict__ cursor, int N)
{
    int idx = blockIdx.x * 256 + threadIdx.x;
    int stride = gridDim.x * 256;
    for (int i = idx; i < N * CURS; i += stride) cursor[i] = 0;
    if (idx < 128 * 128) {
        int n = idx >> 7, k = idx & 127;
        W1t[idx] = f2bf(W1[(size_t)k * 128 + n]);
    }
    if (idx < 64 * 128) {
        int n = idx >> 7, k = idx & 127;
        W2t[idx] = f2bf(W2[(size_t)k * 64 + n]);
    }
}

// ---------------------------------------------------------------------------
// MFMA GEMM body (gemm1): Y[N,128] = bf16(A[N,128] @ W1).
// Verified gfx950 layouts: A/B frag [lane&15][quad*8+j]; C/D col=lane&15,
// row=quad*4+reg. x read exactly once -> NT.
// ---------------------------------------------------------------------------
static __device__ __forceinline__ void gemm1_body(
    const float* __restrict__ A, const unsigned short* __restrict__ Wt,
    unsigned short* __restrict__ Y, int N, int bid)
{
    const int lane = threadIdx.x & 63;
    const int wave = threadIdx.x >> 6;
    const int quad = lane >> 4;
    const int l16  = lane & 15;
    const int row0 = bid * 64 + wave * 16;
    int arow = row0 + l16;
    if (arow > N - 1) arow = N - 1;      // clamp: stores guarded below

    short8 af[4];
    const float* ap = A + (size_t)arow * 128 + quad * 8;
    #pragma unroll
    for (int kt = 0; kt < 4; ++kt) {
        const floatx4* p = (const floatx4*)(ap + kt * 32);
        floatx4 lo = __builtin_nontemporal_load(p);
        floatx4 hi = __builtin_nontemporal_load(p + 1);
        short8 t;
        t[0] = (short)f2bf(lo[0]); t[1] = (short)f2bf(lo[1]);
        t[2] = (short)f2bf(lo[2]); t[3] = (short)f2bf(lo[3]);
        t[4] = (short)f2bf(hi[0]); t[5] = (short)f2bf(hi[1]);
        t[6] = (short)f2bf(hi[2]); t[7] = (short)f2bf(hi[3]);
        af[kt] = t;
    }

    floatx4 acc[8];
    #pragma unroll
    for (int nt = 0; nt < 8; ++nt) acc[nt] = (floatx4){0.f, 0.f, 0.f, 0.f};

    #pragma unroll
    for (int nt = 0; nt < 8; ++nt) {
        const unsigned short* wp = Wt + (size_t)(nt * 16 + l16) * 128 + quad * 8;
        #pragma unroll
        for (int kt = 0; kt < 4; ++kt) {
            short8 bfr = *(const short8*)(wp + kt * 32);
            acc[nt] = __builtin_amdgcn_mfma_f32_16x16x32_bf16(
                af[kt], bfr, acc[nt], 0, 0, 0);
        }
    }

    #pragma unroll
    for (int nt = 0; nt < 8; ++nt) {
        int col = nt * 16 + l16;
        #pragma unroll
        for (int r = 0; r < 4; ++r) {
            int row = row0 + quad * 4 + r;
            if (row < N)
                Y[(size_t)row * 128 + col] = f2bf(acc[nt][r]);
        }
    }
}

// ---------------------------------------------------------------------------
// Fused dispatch:
//  blocks [0, FB): XCD-range-filtered single-pass ELL build. 8 edges/thread;
//    all predicated atomics issued first (batch), then all ELL stores —
//    overlaps the memory-side atomic round-trips.
//  blocks [FB,..): gemm1 (x@W1 MFMA).
// ---------------------------------------------------------------------------
__global__ __launch_bounds__(256) void fill_ell_gemm1_fused(
    const int* __restrict__ erow, const int* __restrict__ ecol,
    const float* __restrict__ eval, int* __restrict__ cursor,
    unsigned int* __restrict__ ell, int E, int FB, int RSTEP,
    const float* __restrict__ x, const unsigned short* __restrict__ W1t,
    unsigned short* __restrict__ y1b, int N)
{
    if ((int)blockIdx.x < FB) {
        const int g     = blockIdx.x & 7;
        const int chunk = blockIdx.x >> 3;
        const int lo = g * RSTEP;
        const int span = min(RSTEP, N - lo);
        int base = chunk * 2048 + (int)threadIdx.x * 8;
        if (base >= E) return;

        if (base + 8 <= E) {
            int4 ra = *(const int4*)(erow + base);
            int4 rb = *(const int4*)(erow + base + 4);
            int4 ca = *(const int4*)(ecol + base);
            int4 cb = *(const int4*)(ecol + base + 4);
            float4 va = *(const float4*)(eval + base);
            float4 vb = *(const float4*)(eval + base + 4);
            int   rr[8] = {ra.x, ra.y, ra.z, ra.w, rb.x, rb.y, rb.z, rb.w};
            int   cc[8] = {ca.x, ca.y, ca.z, ca.w, cb.x, cb.y, cb.z, cb.w};
            float vv[8] = {va.x, va.y, va.z, va.w, vb.x, vb.y, vb.z, vb.w};
            int p[8];
            // Phase 1: issue all predicated atomics back-to-back (no
            // dependent consumer inside the branch body -> MLP).
            #pragma unroll
            for (int j = 0; j < 8; ++j) {
                bool m = (unsigned)(rr[j] - lo) < (unsigned)span;
                p[j] = m ? atomicAdd(&cursor[(size_t)rr[j] * CURS], 1) : ELLS;
            }
            // Phase 2: predicated stores (one waitcnt covers all atomics).
            #pragma unroll
            for (int j = 0; j < 8; ++j) {
                if (p[j] < ELLS) {   // non-match/overflow sentinel skips
                    unsigned int pk = (unsigned int)cc[j]
                        | ((unsigned int)(int)(vv[j] * 32767.f + 0.5f) << 17);
                    ell[((size_t)rr[j] << 6) + p[j]] = pk;
                }
            }
        } else {
            for (int j = 0; j < 8; ++j) {
                int e = base + j;
                if (e < E) {
                    int r = erow[e];
                    if ((unsigned)(r - lo) < (unsigned)span) {
                        int p = atomicAdd(&cursor[(size_t)r * CURS], 1);
                        if (p < ELLS) {
                            unsigned int pk = (unsigned int)ecol[e]
                                | ((unsigned int)(int)(eval[e] * 32767.f + 0.5f) << 17);
                            ell[((size_t)r << 6) + p] = pk;
                        }
                    }
                }
            }
        }
    } else {
        gemm1_body(x, W1t, y1b, N, blockIdx.x - FB);
    }
}

// ---------------------------------------------------------------------------
// FUSED layer-1 SpMM + gemm2: block = 1024 threads = 16 waves.
//  Phase 1: wave w gathers row (blockIdx*16 + w) with a branchless 8-deep
//    unrolled loop (d rounded to multiple of 8; invalid slots predicated to
//    slot=0 -> col 0, val 0), bias+relu, stores the 128-feat bf16 row to LDS.
//  Phase 2 (after barrier): waves 0..3 each compute one 16x16 col-tile of
//    y2 = h2 @ W2 via 4 MFMAs, A-frags straight from LDS, store y2b bf16.
// ---------------------------------------------------------------------------
__global__ __launch_bounds__(1024, 8) void spmm128_gemm2_fused(
    const int* __restrict__ deg, const unsigned int* __restrict__ ell,
    const unsigned short* __restrict__ y1b, const float* __restrict__ b1,
    const unsigned short* __restrict__ W2t,
    unsigned short* __restrict__ y2b, int N)
{
    __shared__ unsigned short h2s[16 * H2LD];

    const int wave = threadIdx.x >> 6;   // 0..15 = row within tile
    const int lane = threadIdx.x & 63;   // owns feats {2*lane, 2*lane+1}
    const int row  = blockIdx.x * 16 + wave;

    unsigned int pack = 0;
    if (row < N) {
        const unsigned int* xf = (const unsigned int*)y1b;
        int d  = min(deg[(size_t)row * CURS], ELLS);
        int d8 = (d + 7) & ~7;
        const unsigned int* ep = ell + ((size_t)row << 6);

        float ax[8], ay[8];
        #pragma unroll
        for (int j = 0; j < 8; ++j) { ax[j] = 0.f; ay[j] = 0.f; }

        for (int i = 0; i < d8; i += 8) {
            uint4 q0 = *(const uint4*)(ep + i);
            uint4 q1 = *(const uint4*)(ep + i + 4);
            unsigned int s[8] = {q0.x, q0.y, q0.z, q0.w,
                                 q1.x, q1.y, q1.z, q1.w};
            unsigned int sv[8];
            unsigned int u[8];
            #pragma unroll
            for (int j = 0; j < 8; ++j) {
                unsigned int ss = (i + j < d) ? s[j] : 0u;  // predicated
                sv[j] = ss;
                u[j] = xf[((ss & 0x1FFFFu) << 6) | (unsigned)lane];
            }
            #pragma unroll
            for (int j = 0; j < 8; ++j) {
                float vvv = slotval(sv[j]);
                ax[j] = fmaf(vvv, bflo(u[j]), ax[j]);
                ay[j] = fmaf(vvv, bfhi(u[j]), ay[j]);
            }
        }
        float2 b = ((const float2*)b1)[lane];
        float sx = ((ax[0] + ax[1]) + (ax[2] + ax[3]))
                 + ((ax[4] + ax[5]) + (ax[6] + ax[7])) + b.x;
        float sy = ((ay[0] + ay[1]) + (ay[2] + ay[3]))
                 + ((ay[4] + ay[5]) + (ay[6] + ay[7])) + b.y;
        sx = fmaxf(sx, 0.f);
        sy = fmaxf(sy, 0.f);
        pack = (unsigned int)f2bf(sx) | ((unsigned int)f2bf(sy) << 16);
    }
    ((unsigned int*)(h2s + wave * H2LD))[lane] = pack;
    __syncthreads();

    // Phase 2: waves 0..3 -> col-tile nt = wave
    if (wave < 4) {
        const int quad = lane >> 4;
        const int l16  = lane & 15;
        const int nt   = wave;

        short8 af[4];
        #pragma unroll
        for (int kt = 0; kt < 4; ++kt)
            af[kt] = *(const short8*)(h2s + l16 * H2LD + quad * 8 + kt * 32);

        floatx4 acc = (floatx4){0.f, 0.f, 0.f, 0.f};
        const unsigned short* wp = W2t + (size_t)(nt * 16 + l16) * 128 + quad * 8;
        #pragma unroll
        for (int kt = 0; kt < 4; ++kt) {
            short8 bfr = *(const short8*)(wp + kt * 32);
            acc = __builtin_amdgcn_mfma_f32_16x16x32_bf16(af[kt], bfr, acc, 0, 0, 0);
        }

        int col = nt * 16 + l16;
        #pragma unroll
        for (int r = 0; r < 4; ++r) {
            int grow = blockIdx.x * 16 + quad * 4 + r;
            if (grow < N)
                y2b[(size_t)grow * 64 + col] = f2bf(acc[r]);
        }
    }
}

// ---------------------------------------------------------------------------
// SpMM 64-wide (ELL, packed 4B slots): wave per row; halves take contiguous
// 4-slot blocks (half0: [i,i+4), half1: [i+4,i+8)) -> one uint4 slot load,
// 4-deep MLP per half, 8 gathers/wave in flight. shfl_xor(32) combine.
// ---------------------------------------------------------------------------
__global__ __launch_bounds__(256) void spmm_gather64_out(
    const int* __restrict__ deg, const unsigned int* __restrict__ ell,
    const unsigned short* __restrict__ y2b,
    const float* __restrict__ bias, float* __restrict__ out, int N)
{
    int row = (blockIdx.x * 256 + threadIdx.x) >> 6;
    if (row >= N) return;
    int lane = threadIdx.x & 63;
    int half = lane >> 5, fl = lane & 31;
    const unsigned int* xf = (const unsigned int*)y2b;

    int d  = min(deg[(size_t)row * CURS], ELLS);
    int d8 = (d + 7) & ~7;
    const unsigned int* ep = ell + ((size_t)row << 6);

    float ax[4], ay[4];
    #pragma unroll
    for (int j = 0; j < 4; ++j) { ax[j] = 0.f; ay[j] = 0.f; }

    for (int i = half * 4; i < d8; i += 8) {
        uint4 q = *(const uint4*)(ep + i);
        unsigned int s[4] = {q.x, q.y, q.z, q.w};
        unsigned int sv[4];
        unsigned int u[4];
        #pragma unroll
        for (int j = 0; j < 4; ++j) {
            unsigned int ss = (i + j < d) ? s[j] : 0u;
            sv[j] = ss;
            u[j] = xf[((ss & 0x1FFFFu) << 5) | (unsigned)fl];
        }
        #pragma unroll
        for (int j = 0; j < 4; ++j) {
            float vvv = slotval(sv[j]);
            ax[j] = fmaf(vvv, bflo(u[j]), ax[j]);
            ay[j] = fmaf(vvv, bfhi(u[j]), ay[j]);
        }
    }
    float sx = (ax[0] + ax[1]) + (ax[2] + ax[3]);
    float sy = (ay[0] + ay[1]) + (ay[2] + ay[3]);
    sx += __shfl_xor(sx, 32);
    sy += __shfl_xor(sy, 32);
    if (half == 0) {
        float2 b = ((const float2*)bias)[fl];
        floatx2 o; o[0] = sx + b.x; o[1] = sy + b.y;
        __builtin_nontemporal_store(o, (floatx2*)out + (size_t)row * 32 + fl);
    }
}

extern "C" void kernel_launch(void* const* d_in, const int* in_sizes, int n_in,
                              void* d_out, int out_size, void* d_ws, size_t ws_size,
                              hipStream_t stream)
{
    const float* x    = (const float*)d_in[0];
    const int*   erow = (const int*)  d_in[1];
    const int*   ecol = (const int*)  d_in[2];
    const float* eval = (const float*)d_in[3];
    const float* W1   = (const float*)d_in[4];
    const float* b1   = (const float*)d_in[5];
    const float* W2   = (const float*)d_in[6];
    const float* b2   = (const float*)d_in[7];
    float*       out  = (float*)d_out;

    const int N = in_sizes[0] / 128;   // 100000
    const int E = in_sizes[1];         // 1600000
    const int NP = N + 64;             // pad so clamped loads stay in-buffer

    // Workspace (~71 MB)
    unsigned short* y1b = (unsigned short*)d_ws;          // [NP,128] bf16
    unsigned short* y2b = y1b + (size_t)NP * 128;         // [NP,64]  bf16
    unsigned short* W1t = y2b + (size_t)NP * 64;          // [128,128] bf16
    unsigned short* W2t = W1t + 128 * 128;                // [64,128]  bf16
    unsigned int* ell   = (unsigned int*)(W2t + 64 * 128);// [N*64] packed slot
    int*   cursor = (int*)(ell + (size_t)N * ELLS);       // [N*CURS] padded

    const int spmm_blocks  = (N + 3) / 4;
    const int fused_blocks = (N + 15) / 16;               // 6250
    const int mfma_blocks  = (N + 63) / 64;               // 1563
    const int prep_blocks  = (N + 255) / 256;
    const int RSTEP        = (N + 7) / 8;                 // rows per XCD range
    const int chunks       = (E + 2047) / 2048;           // 782
    const int FB           = 8 * chunks;                  // fill blocks

    // ---- Prep: zero cursor, cast/transpose weights ----
    prep_kernel<<<prep_blocks, 256, 0, stream>>>(W1, W2, W1t, W2t, cursor, N);

    // ---- Fused: XCD-filtered single-pass ELL build + gemm1 = bf16(x@W1) ----
    fill_ell_gemm1_fused<<<FB + mfma_blocks, 256, 0, stream>>>(
        erow, ecol, eval, cursor, ell, E, FB, RSTEP, x, W1t, y1b, N);

    // ---- Fused layer-1 SpMM + gemm2: y2b = bf16(relu(A@y1b + b1) @ W2) ----
    spmm128_gemm2_fused<<<fused_blocks, 1024, 0, stream>>>(
        cursor, ell, y1b, b1, W2t, y2b, N);

    // ---- Layer 2 SpMM: out = A@y2b + b2 ----
    spmm_gather64_out<<<spmm_blocks, 256, 0, stream>>>(
        cursor, ell, y2b, b2, out, N);
}

// Round 7
// 299.786 us; speedup vs baseline: 1.1375x; 1.0947x over previous
//
#include <hip/hip_runtime.h>

// GCN forward, reassociated + bf16 tables + MFMA GEMMs + binned ELL build:
//   y1b = bf16(x @ W1)                  (MFMA GEMM, fused with binA)
//   h2  = relu(A @ y1b + b1)            (LDS-resident, never hits global)
//   y2b = bf16(h2 @ W2)                 (MFMA, fused with the SpMM above)
//   out = A @ y2b + b2                  (SpMM 64-wide gather, fp32 out)
// Round 17 (resubmit; R6 was an infra timeout): ZERO global atomics, ZERO
// scattered global stores. R12-R16 showed WRITE_SIZE pinned at ~1 full line
// per edge (partial-line RMW at HBM) regardless of payload/NT/padding/
// chain-length -> the scatter itself is the wall. New build:
//   binA: chunk(4096 edges)/block -> LDS histogram over 256-row buckets ->
//         LDS prefix -> LDS compact -> full-line coalesced slab flush.
//   binB: bucket/block -> gather its chunk segments from slab -> build
//         256x64 ELL tile in LDS (LDS atomics) -> 64KB coalesced flush +
//         exact deg. ELL layout identical to before; deg now dense.

typedef __attribute__((ext_vector_type(8))) short short8;
typedef __attribute__((ext_vector_type(4))) float floatx4;
typedef __attribute__((ext_vector_type(2))) float floatx2;

#define ELLS 64    // ELL stride (slots/row)
#define H2LD 136   // LDS row stride in shorts (128 + 8 pad)
#define RW   256   // rows per bucket (binB LDS tile: 256*64*4B = 64 KB)
#define CH   4096  // edges per binA chunk
#define EPT  16    // edges per thread in binA (4096/256)
#define MAXB 400   // static LDS bound for bucket count (N=100K -> 391)

static __device__ __forceinline__ unsigned short f2bf(float f) {
    unsigned int u = __builtin_bit_cast(unsigned int, f);
    u += 0x7fffu + ((u >> 16) & 1u);        // round-to-nearest-even
    return (unsigned short)(u >> 16);
}
static __device__ __forceinline__ float bflo(unsigned int u) {
    return __builtin_bit_cast(float, u << 16);
}
static __device__ __forceinline__ float bfhi(unsigned int u) {
    return __builtin_bit_cast(float, u & 0xffff0000u);
}
// packed ELL slot: low 17 bits = col, high 15 bits = val*32767
static __device__ __forceinline__ float slotval(unsigned int s) {
    return (float)(s >> 17) * (1.0f / 32767.0f);
}

// ---------------------------------------------------------------------------
// Prep: W1[128,128] -> W1t[128][128] bf16; W2[128,64] -> W2t[64][128] bf16
// ---------------------------------------------------------------------------
__global__ __launch_bounds__(256) void prep_kernel(
    const float* __restrict__ W1, const float* __restrict__ W2,
    unsigned short* __restrict__ W1t, unsigned short* __restrict__ W2t)
{
    int idx = blockIdx.x * 256 + threadIdx.x;
    if (idx < 128 * 128) {
        int n = idx >> 7, k = idx & 127;
        W1t[idx] = f2bf(W1[(size_t)k * 128 + n]);
    }
    if (idx < 64 * 128) {
        int n = idx >> 7, k = idx & 127;
        W2t[idx] = f2bf(W2[(size_t)k * 64 + n]);
    }
}

// ---------------------------------------------------------------------------
// MFMA GEMM body (gemm1): Y[N,128] = bf16(A[N,128] @ W1).
// Verified gfx950 layouts: A/B frag [lane&15][quad*8+j]; C/D col=lane&15,
// row=quad*4+reg. x read exactly once -> NT.
// ---------------------------------------------------------------------------
static __device__ __forceinline__ void gemm1_body(
    const float* __restrict__ A, const unsigned short* __restrict__ Wt,
    unsigned short* __restrict__ Y, int N, int bid)
{
    const int lane = threadIdx.x & 63;
    const int wave = threadIdx.x >> 6;
    const int quad = lane >> 4;
    const int l16  = lane & 15;
    const int row0 = bid * 64 + wave * 16;
    int arow = row0 + l16;
    if (arow > N - 1) arow = N - 1;      // clamp: stores guarded below

    short8 af[4];
    const float* ap = A + (size_t)arow * 128 + quad * 8;
    #pragma unroll
    for (int kt = 0; kt < 4; ++kt) {
        const floatx4* p = (const floatx4*)(ap + kt * 32);
        floatx4 lo = __builtin_nontemporal_load(p);
        floatx4 hi = __builtin_nontemporal_load(p + 1);
        short8 t;
        t[0] = (short)f2bf(lo[0]); t[1] = (short)f2bf(lo[1]);
        t[2] = (short)f2bf(lo[2]); t[3] = (short)f2bf(lo[3]);
        t[4] = (short)f2bf(hi[0]); t[5] = (short)f2bf(hi[1]);
        t[6] = (short)f2bf(hi[2]); t[7] = (short)f2bf(hi[3]);
        af[kt] = t;
    }

    floatx4 acc[8];
    #pragma unroll
    for (int nt = 0; nt < 8; ++nt) acc[nt] = (floatx4){0.f, 0.f, 0.f, 0.f};

    #pragma unroll
    for (int nt = 0; nt < 8; ++nt) {
        const unsigned short* wp = Wt + (size_t)(nt * 16 + l16) * 128 + quad * 8;
        #pragma unroll
        for (int kt = 0; kt < 4; ++kt) {
            short8 bfr = *(const short8*)(wp + kt * 32);
            acc[nt] = __builtin_amdgcn_mfma_f32_16x16x32_bf16(
                af[kt], bfr, acc[nt], 0, 0, 0);
        }
    }

    #pragma unroll
    for (int nt = 0; nt < 8; ++nt) {
        int col = nt * 16 + l16;
        #pragma unroll
        for (int r = 0; r < 4; ++r) {
            int row = row0 + quad * 4 + r;
            if (row < N)
                Y[(size_t)row * 128 + col] = f2bf(acc[nt][r]);
        }
    }
}

// ---------------------------------------------------------------------------
// Fused dispatch:
//  blocks [0, NC): binA — chunk histogram/compact/coalesced slab flush.
//  blocks [NC,..): gemm1 (x@W1 MFMA).
//  slab entry: .x = col | (row_in_bucket << 17), .y = fp32 val bits.
// ---------------------------------------------------------------------------
__global__ __launch_bounds__(256) void binA_gemm1_fused(
    const int* __restrict__ erow, const int* __restrict__ ecol,
    const float* __restrict__ eval,
    uint2* __restrict__ slab, unsigned int* __restrict__ offsT,
    int E, int NC, int NB,
    const float* __restrict__ x, const unsigned short* __restrict__ W1t,
    unsigned short* __restrict__ y1b, int N)
{
    __shared__ unsigned int hist[MAXB + 1];
    __shared__ uint2 compact[CH];

    if ((int)blockIdx.x < NC) {
        const int t     = threadIdx.x;
        const int chunk = blockIdx.x;

        for (int i = t; i <= NB; i += 256) hist[i] = 0;
        __syncthreads();

        int base = chunk * CH + t * EPT;
        unsigned int w0[EPT];   // col | (row_in_bucket << 17)
        unsigned int vb[EPT];   // fp32 val bits
        int bk[EPT], rk[EPT];

        if (base + EPT <= E) {
            #pragma unroll
            for (int q = 0; q < 4; ++q) {
                int4   r4 = *(const int4*)(erow + base + q * 4);
                int4   c4 = *(const int4*)(ecol + base + q * 4);
                float4 v4 = *(const float4*)(eval + base + q * 4);
                int rr[4]   = {r4.x, r4.y, r4.z, r4.w};
                int cc[4]   = {c4.x, c4.y, c4.z, c4.w};
                float vv[4] = {v4.x, v4.y, v4.z, v4.w};
                #pragma unroll
                for (int j = 0; j < 4; ++j) {
                    int i = q * 4 + j;
                    bk[i] = rr[j] >> 8;
                    w0[i] = (unsigned int)cc[j]
                          | (((unsigned int)rr[j] & (RW - 1)) << 17);
                    vb[i] = __builtin_bit_cast(unsigned int, vv[j]);
                }
            }
        } else {
            #pragma unroll
            for (int j = 0; j < EPT; ++j) {
                int e = base + j;
                if (e < E) {
                    int r = erow[e];
                    bk[j] = r >> 8;
                    w0[j] = (unsigned int)ecol[e]
                          | (((unsigned int)r & (RW - 1)) << 17);
                    vb[j] = __builtin_bit_cast(unsigned int, eval[e]);
                } else {
                    bk[j] = NB;  // invalid bucket, skipped by binB
                    w0[j] = 0u; vb[j] = 0u;
                }
            }
        }

        #pragma unroll
        for (int j = 0; j < EPT; ++j)
            rk[j] = (int)atomicAdd(&hist[bk[j]], 1u);
        __syncthreads();

        if (t == 0) {            // exclusive prefix over NB+1 buckets
            unsigned int run = 0;
            for (int i = 0; i <= NB; ++i) {
                unsigned int c = hist[i];
                hist[i] = run;
                run += c;
            }
        }
        __syncthreads();

        #pragma unroll
        for (int j = 0; j < EPT; ++j) {
            unsigned int pos = hist[bk[j]] + (unsigned int)rk[j];
            uint2 e; e.x = w0[j]; e.y = vb[j];
            compact[pos] = e;
        }
        __syncthreads();

        // full-line coalesced flush of the whole chunk
        uint2* sp = slab + (size_t)chunk * CH;
        #pragma unroll
        for (int s = 0; s < EPT; ++s)
            sp[s * 256 + t] = compact[s * 256 + t];
        // per-chunk exclusive bucket offsets (NB+1 entries)
        unsigned int* op = offsT + (size_t)chunk * (NB + 1);
        for (int i = t; i <= NB; i += 256) op[i] = hist[i];
    } else {
        gemm1_body(x, W1t, y1b, N, blockIdx.x - NC);
    }
}

// ---------------------------------------------------------------------------
// binB: block b builds the ELL tile for rows [b*RW, (b+1)*RW) in LDS from
// the slab's per-chunk segments, then flushes 64 KB coalesced + deg.
// ---------------------------------------------------------------------------
__global__ __launch_bounds__(256) void binB(
    const uint2* __restrict__ slab, const unsigned int* __restrict__ offsT,
    unsigned int* __restrict__ ell, int* __restrict__ deg,
    int NC, int NB, int N)
{
    __shared__ unsigned int ell_lds[RW * ELLS];   // 64 KB
    __shared__ unsigned int cur[RW];

    const int t = threadIdx.x;
    const int b = blockIdx.x;

    for (int i = t; i < RW; i += 256) cur[i] = 0;
    __syncthreads();

    const int grp = t >> 5;     // 8 chunk-groups of 32 lanes
    const int sl  = t & 31;
    for (int cbase = 0; cbase < NC; cbase += 8) {
        int c = cbase + grp;
        if (c < NC) {
            const unsigned int* op = offsT + (size_t)c * (NB + 1) + b;
            unsigned int off = op[0];
            unsigned int end = op[1];
            const uint2* sp = slab + (size_t)c * CH;
            for (unsigned int i = off + (unsigned)sl; i < end; i += 32) {
                uint2 e = sp[i];
                unsigned int rin = e.x >> 17;
                unsigned int col = e.x & 0x1FFFFu;
                float v = __builtin_bit_cast(float, e.y);
                unsigned int q = (unsigned int)(int)(v * 32767.f + 0.5f);
                unsigned int p = atomicAdd(&cur[rin], 1u);
                if (p < ELLS)
                    ell_lds[rin * ELLS + p] = col | (q << 17);
            }
        }
    }
    __syncthreads();

    // coalesced 64 KB flush (uint4)
    const uint4* src = (const uint4*)ell_lds;
    uint4* dst = (uint4*)(ell + (size_t)b * RW * ELLS);
    #pragma unroll
    for (int s = 0; s < (RW * ELLS / 4) / 256; ++s)   // 16 steps
        dst[s * 256 + t] = src[s * 256 + t];

    int row = b * RW + t;
    if (row < N) deg[row] = min((int)cur[t], ELLS);
}

// ---------------------------------------------------------------------------
// FUSED layer-1 SpMM + gemm2: block = 1024 threads = 16 waves.
//  Phase 1: wave w gathers row (blockIdx*16 + w) with a branchless 8-deep
//    unrolled loop (d rounded to multiple of 8; invalid slots predicated to
//    slot=0 -> col 0, val 0), bias+relu, stores the 128-feat bf16 row to LDS.
//  Phase 2 (after barrier): waves 0..3 each compute one 16x16 col-tile of
//    y2 = h2 @ W2 via 4 MFMAs, A-frags straight from LDS, store y2b bf16.
// ---------------------------------------------------------------------------
__global__ __launch_bounds__(1024, 8) void spmm128_gemm2_fused(
    const int* __restrict__ deg, const unsigned int* __restrict__ ell,
    const unsigned short* __restrict__ y1b, const float* __restrict__ b1,
    const unsigned short* __restrict__ W2t,
    unsigned short* __restrict__ y2b, int N)
{
    __shared__ unsigned short h2s[16 * H2LD];

    const int wave = threadIdx.x >> 6;   // 0..15 = row within tile
    const int lane = threadIdx.x & 63;   // owns feats {2*lane, 2*lane+1}
    const int row  = blockIdx.x * 16 + wave;

    unsigned int pack = 0;
    if (row < N) {
        const unsigned int* xf = (const unsigned int*)y1b;
        int d  = min(deg[row], ELLS);
        int d8 = (d + 7) & ~7;
        const unsigned int* ep = ell + ((size_t)row << 6);

        float ax[8], ay[8];
        #pragma unroll
        for (int j = 0; j < 8; ++j) { ax[j] = 0.f; ay[j] = 0.f; }

        for (int i = 0; i < d8; i += 8) {
            uint4 q0 = *(const uint4*)(ep + i);
            uint4 q1 = *(const uint4*)(ep + i + 4);
            unsigned int s[8] = {q0.x, q0.y, q0.z, q0.w,
                                 q1.x, q1.y, q1.z, q1.w};
            unsigned int sv[8];
            unsigned int u[8];
            #pragma unroll
            for (int j = 0; j < 8; ++j) {
                unsigned int ss = (i + j < d) ? s[j] : 0u;  // predicated
                sv[j] = ss;
                u[j] = xf[((ss & 0x1FFFFu) << 6) | (unsigned)lane];
            }
            #pragma unroll
            for (int j = 0; j < 8; ++j) {
                float vvv = slotval(sv[j]);
                ax[j] = fmaf(vvv, bflo(u[j]), ax[j]);
                ay[j] = fmaf(vvv, bfhi(u[j]), ay[j]);
            }
        }
        float2 b = ((const float2*)b1)[lane];
        float sx = ((ax[0] + ax[1]) + (ax[2] + ax[3]))
                 + ((ax[4] + ax[5]) + (ax[6] + ax[7])) + b.x;
        float sy = ((ay[0] + ay[1]) + (ay[2] + ay[3]))
                 + ((ay[4] + ay[5]) + (ay[6] + ay[7])) + b.y;
        sx = fmaxf(sx, 0.f);
        sy = fmaxf(sy, 0.f);
        pack = (unsigned int)f2bf(sx) | ((unsigned int)f2bf(sy) << 16);
    }
    ((unsigned int*)(h2s + wave * H2LD))[lane] = pack;
    __syncthreads();

    // Phase 2: waves 0..3 -> col-tile nt = wave
    if (wave < 4) {
        const int quad = lane >> 4;
        const int l16  = lane & 15;
        const int nt   = wave;

        short8 af[4];
        #pragma unroll
        for (int kt = 0; kt < 4; ++kt)
            af[kt] = *(const short8*)(h2s + l16 * H2LD + quad * 8 + kt * 32);

        floatx4 acc = (floatx4){0.f, 0.f, 0.f, 0.f};
        const unsigned short* wp = W2t + (size_t)(nt * 16 + l16) * 128 + quad * 8;
        #pragma unroll
        for (int kt = 0; kt < 4; ++kt) {
            short8 bfr = *(const short8*)(wp + kt * 32);
            acc = __builtin_amdgcn_mfma_f32_16x16x32_bf16(af[kt], bfr, acc, 0, 0, 0);
        }

        int col = nt * 16 + l16;
        #pragma unroll
        for (int r = 0; r < 4; ++r) {
            int grow = blockIdx.x * 16 + quad * 4 + r;
            if (grow < N)
                y2b[(size_t)grow * 64 + col] = f2bf(acc[r]);
        }
    }
}

// ---------------------------------------------------------------------------
// SpMM 64-wide (ELL, packed 4B slots): wave per row; halves take contiguous
// 4-slot blocks (half0: [i,i+4), half1: [i+4,i+8)) -> one uint4 slot load,
// 4-deep MLP per half, 8 gathers/wave in flight. shfl_xor(32) combine.
// ---------------------------------------------------------------------------
__global__ __launch_bounds__(256) void spmm_gather64_out(
    const int* __restrict__ deg, const unsigned int* __restrict__ ell,
    const unsigned short* __restrict__ y2b,
    const float* __restrict__ bias, float* __restrict__ out, int N)
{
    int row = (blockIdx.x * 256 + threadIdx.x) >> 6;
    if (row >= N) return;
    int lane = threadIdx.x & 63;
    int half = lane >> 5, fl = lane & 31;
    const unsigned int* xf = (const unsigned int*)y2b;

    int d  = min(deg[row], ELLS);
    int d8 = (d + 7) & ~7;
    const unsigned int* ep = ell + ((size_t)row << 6);

    float ax[4], ay[4];
    #pragma unroll
    for (int j = 0; j < 4; ++j) { ax[j] = 0.f; ay[j] = 0.f; }

    for (int i = half * 4; i < d8; i += 8) {
        uint4 q = *(const uint4*)(ep + i);
        unsigned int s[4] = {q.x, q.y, q.z, q.w};
        unsigned int sv[4];
        unsigned int u[4];
        #pragma unroll
        for (int j = 0; j < 4; ++j) {
            unsigned int ss = (i + j < d) ? s[j] : 0u;
            sv[j] = ss;
            u[j] = xf[((ss & 0x1FFFFu) << 5) | (unsigned)fl];
        }
        #pragma unroll
        for (int j = 0; j < 4; ++j) {
            float vvv = slotval(sv[j]);
            ax[j] = fmaf(vvv, bflo(u[j]), ax[j]);
            ay[j] = fmaf(vvv, bfhi(u[j]), ay[j]);
        }
    }
    float sx = (ax[0] + ax[1]) + (ax[2] + ax[3]);
    float sy = (ay[0] + ay[1]) + (ay[2] + ay[3]);
    sx += __shfl_xor(sx, 32);
    sy += __shfl_xor(sy, 32);
    if (half == 0) {
        float2 b = ((const float2*)bias)[fl];
        floatx2 o; o[0] = sx + b.x; o[1] = sy + b.y;
        __builtin_nontemporal_store(o, (floatx2*)out + (size_t)row * 32 + fl);
    }
}

extern "C" void kernel_launch(void* const* d_in, const int* in_sizes, int n_in,
                              void* d_out, int out_size, void* d_ws, size_t ws_size,
                              hipStream_t stream)
{
    const float* x    = (const float*)d_in[0];
    const int*   erow = (const int*)  d_in[1];
    const int*   ecol = (const int*)  d_in[2];
    const float* eval = (const float*)d_in[3];
    const float* W1   = (const float*)d_in[4];
    const float* b1   = (const float*)d_in[5];
    const float* W2   = (const float*)d_in[6];
    const float* b2   = (const float*)d_in[7];
    float*       out  = (float*)d_out;

    const int N = in_sizes[0] / 128;   // 100000
    const int E = in_sizes[1];         // 1600000
    const int NP = N + 64;             // pad so clamped loads stay in-buffer
    const int NB = (N + RW - 1) / RW;  // 391 buckets
    const int NC = (E + CH - 1) / CH;  // 391 chunks

    // Workspace (~78 MB), all sections 16B-aligned by construction
    unsigned short* y1b = (unsigned short*)d_ws;            // [NP,128] bf16
    unsigned short* y2b = y1b + (size_t)NP * 128;           // [NP,64]  bf16
    unsigned short* W1t = y2b + (size_t)NP * 64;            // [128,128] bf16
    unsigned short* W2t = W1t + 128 * 128;                  // [64,128]  bf16
    unsigned int* ell   = (unsigned int*)(W2t + 64 * 128);  // [NB*RW*64] slots
    uint2* slab         = (uint2*)(ell + (size_t)NB * RW * ELLS);  // [NC*CH]
    unsigned int* offsT = (unsigned int*)(slab + (size_t)NC * CH); // [NC*(NB+1)]
    int* deg            = (int*)(offsT + (size_t)NC * (NB + 1));   // [N]

    const int spmm_blocks  = (N + 3) / 4;
    const int fused_blocks = (N + 15) / 16;               // 6250
    const int mfma_blocks  = (N + 63) / 64;               // 1563
    const int prep_blocks  = (128 * 128 + 255) / 256;     // 64

    // ---- Prep: cast/transpose weights ----
    prep_kernel<<<prep_blocks, 256, 0, stream>>>(W1, W2, W1t, W2t);

    // ---- binA (chunk binning, coalesced slab) + gemm1 = bf16(x@W1) ----
    binA_gemm1_fused<<<NC + mfma_blocks, 256, 0, stream>>>(
        erow, ecol, eval, slab, offsT, E, NC, NB, x, W1t, y1b, N);

    // ---- binB: bucket -> ELL tile in LDS -> coalesced flush ----
    binB<<<NB, 256, 0, stream>>>(slab, offsT, ell, deg, NC, NB, N);

    // ---- Fused layer-1 SpMM + gemm2: y2b = bf16(relu(A@y1b + b1) @ W2) ----
    spmm128_gemm2_fused<<<fused_blocks, 1024, 0, stream>>>(
        deg, ell, y1b, b1, W2t, y2b, N);

    // ---- Layer 2 SpMM: out = A@y2b + b2 ----
    spmm_gather64_out<<<spmm_blocks, 256, 0, stream>>>(
        deg, ell, y2b, b2, out, N);
}